// Round 7
// baseline (31.073 us; speedup 1.0000x reference)
//
#include <hip/hip_runtime.h>
#include <hip/hip_bf16.h>

#define B_ 8
#define G_ 1024
#define HD_ 1024
#define EPS_ 1e-5f

// NOTE: The reference's BatchNorm over the G axis (training mode, batch stats)
// makes the output invariant to any per-(b,j) constant added to H @ fc_w.T.
// The broadcast-qemb half of H and fc_b are such constants -> the whole GIN
// pipeline cannot affect d_out. Only gPos, allDBGEmb, fc_w[:,1024:], bn3, fc2
// matter. (Verified R3 vs R4: identical absmax.)
// R5 lesson: cooperative launch + grid.sync costs ~45 us here -> stay multi-kernel.

typedef __attribute__((ext_vector_type(8))) short bf16x8;
typedef __attribute__((ext_vector_type(4))) float f32x4;

__device__ inline short bf1(float x) {
    return (short)__builtin_bit_cast(unsigned short, __float2bfloat16(x));
}
__device__ inline bf16x8 cvt8(float4 a, float4 b) {
    bf16x8 o;
    o[0] = bf1(a.x); o[1] = bf1(a.y); o[2] = bf1(a.z); o[3] = bf1(a.w);
    o[4] = bf1(b.x); o[5] = bf1(b.y); o[6] = bf1(b.z); o[7] = bf1(b.w);
    return o;
}
__device__ inline float bf2f(unsigned short u) {
    return __builtin_bit_cast(float, (unsigned)u << 16);
}

// ---------- fc_w[:,1024:2048] -> bf16 in MFMA B-fragment order ----------
// frag f = kt*8 + jblk (kt = k/32, jblk = j/16); lane l holds
// B[k = kt*32 + (l>>4)*8 + i][j = jblk*16 + (l&15)], i = 0..7.
__global__ __launch_bounds__(256) void k_w2cvt(const float* __restrict__ fc_w,
                                               short* __restrict__ w2arr) {
    int gid = blockIdx.x * 256 + threadIdx.x;  // 0 .. 32*8*64-1
    int kt = gid >> 9;
    int jblk = (gid >> 6) & 7;
    int lane = gid & 63;
    int j = jblk * 16 + (lane & 15);
    int k = kt * 32 + (lane >> 4) * 8;
    const float4* sp = (const float4*)&fc_w[(size_t)j * (2 * HD_) + HD_ + k];
    *(bf16x8*)&w2arr[(size_t)gid * 8] = cvt8(sp[0], sp[1]);
}

#define SLABW 258  // 32 rows * 8 shorts + 2 pad per 8-k slab

// ---------- z[b][g][j] = emb[gPos[b][g]] . fc_w[j][1024:2048] ----------
// grid (32, 8), 512 thr = 8 waves. Single-stage: whole 32-row A tile
// (f32->bf16, 64.5 KB LDS) with one barrier, then pure MFMA sweep.
// Wave jq = 0..7 computes 32g x 16j (A from LDS x2, B direct from L2).
__global__ __launch_bounds__(512) void k_gemm(const int* __restrict__ gPos,
                                              const float* __restrict__ emb,
                                              const short* __restrict__ w2arr,
                                              short* __restrict__ zb,
                                              float* __restrict__ ps,
                                              float* __restrict__ pq) {
    int b = blockIdx.y, gblk = blockIdx.x;
    int gbase = gblk * 32;
    int tid = threadIdx.x;
    int jq = tid >> 6, lane = tid & 63;
    int l15 = lane & 15, kb = lane >> 4;

    __shared__ short As[128 * SLABW];

    // stage whole A tile: thread (row = tid>>4, cp = tid&15), 16 dwordx4 loads
    {
        int arow = tid >> 4, acp = tid & 15;
        const float* abase = emb + (size_t)gPos[b * G_ + gbase + arow] * HD_;
#pragma unroll
        for (int i = 0; i < 8; ++i) {
            int k = i * 128 + acp * 8;  // per-instr: 16 cp lanes cover 512 B/row
            const float4* ap = (const float4*)(abase + k);
            *(bf16x8*)&As[(i * 16 + acp) * SLABW + arow * 8] = cvt8(ap[0], ap[1]);
        }
    }
    __syncthreads();

    f32x4 acc0 = {0.f, 0.f, 0.f, 0.f}, acc1 = {0.f, 0.f, 0.f, 0.f};
#pragma unroll 4
    for (int kt = 0; kt < 32; ++kt) {
        int f = kt * 8 + jq;
        bf16x8 bv = *(const bf16x8*)&w2arr[((size_t)f * 64 + lane) * 8];
        bf16x8 a0 = *(const bf16x8*)&As[(kt * 4 + kb) * SLABW + l15 * 8];
        bf16x8 a1 = *(const bf16x8*)&As[(kt * 4 + kb) * SLABW + (16 + l15) * 8];
        acc0 = __builtin_amdgcn_mfma_f32_16x16x32_bf16(a0, bv, acc0, 0, 0, 0);
        acc1 = __builtin_amdgcn_mfma_f32_16x16x32_bf16(a1, bv, acc1, 0, 0, 0);
    }

    // epilogue: bf16 z write + per-(b,gblk) BN partials from exact f32 acc
    int jcol = jq * 16 + l15;
    float s = 0.f, q = 0.f;
#pragma unroll
    for (int r = 0; r < 4; ++r) {  // C/D: col=lane&15, row=(lane>>4)*4+reg
        float v0 = acc0[r], v1 = acc1[r];
        int g0 = gbase + kb * 4 + r;
        int g1 = g0 + 16;
        zb[(size_t)(b * G_ + g0) * 128 + jcol] = bf1(v0);
        zb[(size_t)(b * G_ + g1) * 128 + jcol] = bf1(v1);
        s += v0 + v1;
        q += v0 * v0 + v1 * v1;
    }
    s += __shfl_xor(s, 16, 64); s += __shfl_xor(s, 32, 64);
    q += __shfl_xor(q, 16, 64); q += __shfl_xor(q, 32, 64);
    if (lane < 16) {
        ps[(b * 32 + gblk) * 128 + jcol] = s;
        pq[(b * 32 + gblk) * 128 + jcol] = q;
    }
}

// ---------- fused BN3 stats + apply + relu + fc2 + sigmoid ----------
// grid (16, 8), 256 thr; block reduces its graph's 32 partials (redundant x16,
// 32 KB L2) then processes 64 g rows, one row per wave-iteration.
__global__ __launch_bounds__(256) void k_final(const short* __restrict__ zb,
                                               const float* __restrict__ ps,
                                               const float* __restrict__ pq,
                                               const float* __restrict__ g3,
                                               const float* __restrict__ b3,
                                               const float* __restrict__ fc2w,
                                               const float* __restrict__ fc2b,
                                               float* __restrict__ out) {
    int b = blockIdx.y, gseg = blockIdx.x;
    int tid = threadIdx.x, wave = tid >> 6, lane = tid & 63;
    __shared__ float scL[128], shL[128];
    if (tid < 128) {
        int j = tid;
        float s = 0.f, q = 0.f;
#pragma unroll 8
        for (int t = 0; t < 32; ++t) {
            s += ps[(b * 32 + t) * 128 + j];
            q += pq[(b * 32 + t) * 128 + j];
        }
        float mu = s * (1.f / G_);
        float var = q * (1.f / G_) - mu * mu;
        float sc = g3[j] * rsqrtf(var + EPS_);
        scL[j] = sc;
        shL[j] = b3[j] - mu * sc;
    }
    __syncthreads();
    int j0 = lane * 2;
    float sc0 = scL[j0], sc1 = scL[j0 + 1];
    float sh0 = shL[j0], sh1 = shL[j0 + 1];
    float w0 = fc2w[j0], w1 = fc2w[j0 + 1], bias = fc2b[0];
#pragma unroll
    for (int it = 0; it < 16; ++it) {
        int g = gseg * 64 + it * 4 + wave;
        const ushort2* zr = (const ushort2*)(zb + (size_t)(b * G_ + g) * 128);
        ushort2 u = zr[lane];
        float acc = fmaxf(fmaf(bf2f(u.x), sc0, sh0), 0.f) * w0 +
                    fmaxf(fmaf(bf2f(u.y), sc1, sh1), 0.f) * w1;
        acc += __shfl_xor(acc, 32, 64);
        acc += __shfl_xor(acc, 16, 64);
        acc += __shfl_xor(acc, 8, 64);
        acc += __shfl_xor(acc, 4, 64);
        acc += __shfl_xor(acc, 2, 64);
        acc += __shfl_xor(acc, 1, 64);
        if (lane == 0) out[b * G_ + g] = 1.f / (1.f + expf(-(acc + bias)));
    }
}

extern "C" void kernel_launch(void* const* d_in, const int* in_sizes, int n_in,
                              void* d_out, int out_size, void* d_ws, size_t ws_size,
                              hipStream_t stream) {
    const int*   gPos = (const int*)d_in[3];
    const float* emb  = (const float*)d_in[4];
    const float* fc_w = (const float*)d_in[11];
    const float* bn3g = (const float*)d_in[13];
    const float* bn3b = (const float*)d_in[14];
    const float* fc2w = (const float*)d_in[15];
    const float* fc2b = (const float*)d_in[16];
    float* out = (float*)d_out;

    char* w = (char*)d_ws;
    short* zb    = (short*)w; w += (size_t)B_ * G_ * 128 * 2;   // 2 MB
    short* w2arr = (short*)w; w += (size_t)128 * HD_ * 2;       // 256 KB
    float* ps    = (float*)w; w += (size_t)B_ * 32 * 128 * 4;   // 128 KB
    float* pq    = (float*)w; w += (size_t)B_ * 32 * 128 * 4;   // 128 KB

    k_w2cvt<<<64, 256, 0, stream>>>(fc_w, w2arr);
    k_gemm<<<dim3(32, B_), 512, 0, stream>>>(gPos, emb, w2arr, zb, ps, pq);
    k_final<<<dim3(16, B_), 256, 0, stream>>>(zb, ps, pq, bn3g, bn3b, fc2w, fc2b, out);
}